// Round 2
// baseline (2746.509 us; speedup 1.0000x reference)
//
#include <hip/hip_runtime.h>
#include <math.h>
#include <stdint.h>

#define N_TOK 16384
#define DIM   1024
#define NEXP  8
#define HID   2048
#define OUTD  1024
#define PADTOT 33792   // 2*N_TOK + 8*128 : padded compacted-row upper bound (264 tiles)

typedef __attribute__((ext_vector_type(8))) short short8;
typedef __attribute__((ext_vector_type(8))) _Float16 f16x8;
typedef __attribute__((ext_vector_type(4))) float f32x4;
typedef __attribute__((ext_vector_type(4))) unsigned short u16x4;

__device__ __forceinline__ unsigned short f2h(float f) {
  return __builtin_bit_cast(unsigned short, (_Float16)f);   // RNE
}
__device__ __forceinline__ float gelu_exact(float a) {
  return 0.5f * a * (1.0f + erff(a * 0.70710678118654752f));
}

// ---------------- gate: fp64 for routing robustness, no LDS ----------------
__global__ __launch_bounds__(256) void gate_kernel(
    const float* __restrict__ x, const float* __restrict__ Wg1,
    const float* __restrict__ Wg2,
    int* __restrict__ tok_e, float* __restrict__ tok_w, int* __restrict__ cnt)
{
  const int tid = threadIdx.x;
  const int lane = tid & 63, wid = tid >> 6;
  const int wave_global = blockIdx.x * 4 + wid;     // 0..1023
  const f32x4* __restrict__ Wg1v = (const f32x4*)Wg1;   // [1024][4]
  for (int t = 0; t < N_TOK / 1024; ++t) {
    const int n = wave_global * (N_TOK / 1024) + t;
    double acc[16];
#pragma unroll
    for (int j = 0; j < 16; ++j) acc[j] = 0.0;
    for (int it = 0; it < DIM / 64; ++it) {
      int d = it * 64 + lane;
      double xv = (double)x[(size_t)n * DIM + d];
      f32x4 w0 = Wg1v[(size_t)d * 4 + 0];
      f32x4 w1 = Wg1v[(size_t)d * 4 + 1];
      f32x4 w2 = Wg1v[(size_t)d * 4 + 2];
      f32x4 w3 = Wg1v[(size_t)d * 4 + 3];
#pragma unroll
      for (int q = 0; q < 4; ++q) {
        acc[q]      += xv * (double)w0[q];
        acc[4 + q]  += xv * (double)w1[q];
        acc[8 + q]  += xv * (double)w2[q];
        acc[12 + q] += xv * (double)w3[q];
      }
    }
#pragma unroll
    for (int j = 0; j < 16; ++j) {
#pragma unroll
      for (int s = 32; s > 0; s >>= 1) acc[j] += __shfl_xor(acc[j], s);
    }
    // select acc[lane&15] without dynamic indexing (rule #20)
    const int jl = lane & 15;
    double av = acc[0];
#pragma unroll
    for (int j = 1; j < 16; ++j) av = (jl == j) ? acc[j] : av;
    double tmine = tanh(av);
    const int e = lane & 7;
    double ge = 0.0;
#pragma unroll
    for (int j = 0; j < 16; ++j) {
      double tj = __shfl(tmine, j);
      ge += tj * (double)Wg2[j * 8 + e];
    }
    // softmax over 8 within each 8-lane group
    double m = ge;
#pragma unroll
    for (int s = 1; s < 8; s <<= 1) m = fmax(m, __shfl_xor(m, s));
    double p = exp(ge - m);
    double ssum = p;
#pragma unroll
    for (int s = 1; s < 8; s <<= 1) ssum += __shfl_xor(ssum, s);
    double wsm = p / ssum;
    // top-2 via 64-bit keys (ties -> lowest index, like lax.top_k)
    unsigned long long key =
        (((unsigned long long)__double_as_longlong(wsm)) & ~7ULL) |
        (unsigned long long)(7 - e);
    unsigned long long k1 = key;
#pragma unroll
    for (int s = 1; s < 8; s <<= 1) { unsigned long long o = __shfl_xor(k1, s); k1 = (o > k1) ? o : k1; }
    int e1 = 7 - (int)(k1 & 7ULL);
    unsigned long long k2 = (e == e1) ? 0ULL : key;
#pragma unroll
    for (int s = 1; s < 8; s <<= 1) { unsigned long long o = __shfl_xor(k2, s); k2 = (o > k2) ? o : k2; }
    int e2 = 7 - (int)(k2 & 7ULL);
    double w1v = __longlong_as_double((long long)(k1 & ~7ULL));
    double w2v = __longlong_as_double((long long)(k2 & ~7ULL));
    double inv = 1.0 / (w1v + w2v + 1e-12);
    if (lane == 0) {
      tok_e[2 * n] = e1; tok_e[2 * n + 1] = e2;
      tok_w[2 * n] = (float)(w1v * inv); tok_w[2 * n + 1] = (float)(w2v * inv);
      atomicAdd(&cnt[e1], 1); atomicAdd(&cnt[e2], 1);
    }
  }
}

// offsets padded to multiples of 128 so every 128-row tile is single-expert
__global__ void offsets_kernel(const int* __restrict__ cnt, int* __restrict__ off,
                               int* __restrict__ cur) {
  if (threadIdx.x == 0) {
    int a = 0;
    for (int e = 0; e < NEXP; ++e) {
      off[e] = a; cur[e] = a;
      a += (cnt[e] + 127) & ~127;
    }
    off[NEXP] = a;
  }
}

__global__ __launch_bounds__(256) void scatter_kernel(
    const int* __restrict__ tok_e, const float* __restrict__ tok_w,
    int* __restrict__ cur, int* __restrict__ rows, float* __restrict__ roww)
{
  int n = blockIdx.x * 256 + threadIdx.x;
  if (n >= N_TOK) return;
#pragma unroll
  for (int k = 0; k < 2; ++k) {
    int e = tok_e[2 * n + k];
    int pos = atomicAdd(&cur[e], 1);
    rows[pos] = n;
    roww[pos] = tok_w[2 * n + k];
  }
}

// ---------------- fp32 -> fp16 converts ----------------
__global__ __launch_bounds__(256) void convert_x_kernel(
    const float* __restrict__ x, unsigned short* __restrict__ xh)
{
  size_t i = ((size_t)blockIdx.x * 256 + threadIdx.x) * 8;
  f32x4 a = *(const f32x4*)(x + i);
  f32x4 b = *(const f32x4*)(x + i + 4);
  short8 o;
#pragma unroll
  for (int q = 0; q < 4; ++q) { o[q] = (short)f2h(a[q]); o[q + 4] = (short)f2h(b[q]); }
  *(short8*)(xh + i) = o;
}

// transpose+convert: W[e][K][N] fp32 -> Wt[e][N][K] fp16
__global__ __launch_bounds__(256) void wconv_kernel(
    const float* __restrict__ W, unsigned short* __restrict__ Wt,
    const int K, const int N)
{
  __shared__ float t[32][33];
  const int e = blockIdx.z;
  const float* We = W + (size_t)e * K * N;
  unsigned short* Wte = Wt + (size_t)e * K * N;
  const int n0 = blockIdx.x * 32, k0 = blockIdx.y * 32;
  const int tid = threadIdx.x;
  const int r = tid >> 3, c4 = (tid & 7) * 4;
  f32x4 v = *(const f32x4*)(We + (size_t)(k0 + r) * N + n0 + c4);
  t[r][c4 + 0] = v[0]; t[r][c4 + 1] = v[1]; t[r][c4 + 2] = v[2]; t[r][c4 + 3] = v[3];
  __syncthreads();
  u16x4 o;
#pragma unroll
  for (int q = 0; q < 4; ++q) o[q] = f2h(t[c4 + q][r]);
  *(u16x4*)(Wte + (size_t)(n0 + r) * K + k0 + c4) = o;
}

// ---------------- routed GEMM (fp16 MFMA, fp32 acc) ----------------
// MODE 0: A = gathered xh rows (via rows[]), out = act1f chunk-local (acc+bias)
// MODE 1: A = act2 chunk-local,              out = act1f chunk-local (acc+bias)
// MODE 2: A = act2 chunk-local,              out = d_out via atomicAdd(w*(acc+bias))
template<int MODE>
__global__ __launch_bounds__(256) void gemm_kernel(
    const unsigned short* __restrict__ Abase,
    const unsigned short* __restrict__ Bbase,
    float* __restrict__ Obase,
    const float* __restrict__ bias,
    const int* __restrict__ rows,
    const float* __restrict__ roww,
    const int* __restrict__ off,
    const int K, const int N, const int Astride, const int c0)
{
  const int off8 = off[NEXP];
  const int rowbase = c0 + blockIdx.y * 128;
  if (rowbase >= off8) return;
  int e = 0;
  while (e < NEXP - 1 && rowbase >= off[e + 1]) ++e;
  const int tn = blockIdx.x;

  __shared__ __align__(16) unsigned short ldsA[128 * 64];
  __shared__ __align__(16) unsigned short ldsB[128 * 64];

  const int tid = threadIdx.x, lane = tid & 63, wid = tid >> 6;
  const int wm = wid >> 1, wn = wid & 1;
  const int l15 = lane & 15, lh = lane >> 4;

  f32x4 acc[4][4] = {};

  // staging: chunk c = i*256+tid -> LDS bytes c*16 (linear, lane-contiguous per wave)
  // slot (row, s) holds logical k-chunk s^(row&7): pre-swizzled GLOBAL source (T2 both-sides)
  size_t aoff[4], boff[4];
#pragma unroll
  for (int i = 0; i < 4; ++i) {
    int c = i * 256 + tid;
    int row = c >> 3;
    int kc = ((c & 7) ^ (row & 7)) * 8;
    size_t arow;
    if (MODE == 0) arow = (size_t)rows[rowbase + row];
    else           arow = (size_t)(rowbase - c0 + row);
    aoff[i] = arow * (size_t)Astride + kc;
    boff[i] = ((size_t)e * N + (size_t)(tn * 128 + row)) * K + kc;
  }

  for (int k0 = 0; k0 < K; k0 += 64) {
#pragma unroll
    for (int i = 0; i < 4; ++i) {
      int c = i * 256 + tid;
      __builtin_amdgcn_global_load_lds(
          (const __attribute__((address_space(1))) void*)(Abase + aoff[i] + k0),
          (__attribute__((address_space(3))) void*)(ldsA + (size_t)c * 8), 16, 0, 0);
      __builtin_amdgcn_global_load_lds(
          (const __attribute__((address_space(1))) void*)(Bbase + boff[i] + k0),
          (__attribute__((address_space(3))) void*)(ldsB + (size_t)c * 8), 16, 0, 0);
    }
    __syncthreads();
#pragma unroll
    for (int kk = 0; kk < 2; ++kk) {
      short8 af[4], bf[4];
#pragma unroll
      for (int mi = 0; mi < 4; ++mi) {
        int row = wm * 64 + mi * 16 + l15;
        int chunk = (kk * 4 + lh) ^ (row & 7);
        af[mi] = *(const short8*)(ldsA + row * 64 + chunk * 8);
      }
#pragma unroll
      for (int ni = 0; ni < 4; ++ni) {
        int row = wn * 64 + ni * 16 + l15;
        int chunk = (kk * 4 + lh) ^ (row & 7);
        bf[ni] = *(const short8*)(ldsB + row * 64 + chunk * 8);
      }
#pragma unroll
      for (int mi = 0; mi < 4; ++mi)
#pragma unroll
        for (int ni = 0; ni < 4; ++ni)
          acc[mi][ni] = __builtin_amdgcn_mfma_f32_16x16x32_f16(
              __builtin_bit_cast(f16x8, bf[ni]),
              __builtin_bit_cast(f16x8, af[mi]),
              acc[mi][ni], 0, 0, 0);   // D[n][token]: lane holds token=l15, n=lh*4+q
    }
    __syncthreads();
  }

#pragma unroll
  for (int mi = 0; mi < 4; ++mi) {
    int rowloc = wm * 64 + mi * 16 + l15;
    int g = rowbase + rowloc;
    if (MODE == 2) {
      int token = rows[g];
      float wgt = roww[g];
#pragma unroll
      for (int ni = 0; ni < 4; ++ni) {
        int n = tn * 128 + wn * 64 + ni * 16 + lh * 4;
        f32x4 v = acc[mi][ni];
        f32x4 bv = *(const f32x4*)(bias + (size_t)e * N + n);
#pragma unroll
        for (int q = 0; q < 4; ++q)
          atomicAdd(&Obase[(size_t)token * N + n + q], wgt * (v[q] + bv[q]));
      }
    } else {
      size_t orow = (size_t)(g - c0) * N;
#pragma unroll
      for (int ni = 0; ni < 4; ++ni) {
        int n = tn * 128 + wn * 64 + ni * 16 + lh * 4;
        f32x4 v = acc[mi][ni];
        f32x4 bv = *(const f32x4*)(bias + (size_t)e * N + n);
        f32x4 o;
#pragma unroll
        for (int q = 0; q < 4; ++q) o[q] = v[q] + bv[q];
        *(f32x4*)(Obase + orow + n) = o;
      }
    }
  }
}

// ---------------- LayerNorm + exact GELU: fp32 in, fp16 out ----------------
__global__ __launch_bounds__(256) void ln_gelu_kernel(
    const float* __restrict__ src, unsigned short* __restrict__ dst,
    const float* __restrict__ gam, const float* __restrict__ bet,
    const int* __restrict__ off, const int c0)
{
  const int g = c0 + blockIdx.x;
  if (g >= off[NEXP]) return;
  int e = 0;
  while (e < NEXP - 1 && g >= off[e + 1]) ++e;
  const int tid = threadIdx.x;
  const float* s0 = src + (size_t)(g - c0) * HID;
  f32x4 a = *(const f32x4*)(s0 + tid * 8);
  f32x4 b = *(const f32x4*)(s0 + tid * 8 + 4);
  float s = 0.f, sq = 0.f;
#pragma unroll
  for (int q = 0; q < 4; ++q) { s += a[q] + b[q]; sq += a[q] * a[q] + b[q] * b[q]; }
#pragma unroll
  for (int sh = 32; sh > 0; sh >>= 1) { s += __shfl_xor(s, sh); sq += __shfl_xor(sq, sh); }
  __shared__ float rs_[4], rq_[4];
  const int lane = tid & 63, wid = tid >> 6;
  if (lane == 0) { rs_[wid] = s; rq_[wid] = sq; }
  __syncthreads();
  s  = rs_[0] + rs_[1] + rs_[2] + rs_[3];
  sq = rq_[0] + rq_[1] + rq_[2] + rq_[3];
  const float mu  = s * (1.0f / HID);
  const float var = sq * (1.0f / HID) - mu * mu;
  const float rstd = rsqrtf(var + 1e-5f);
  const float* gp = gam + (size_t)e * HID + tid * 8;
  const float* bp = bet + (size_t)e * HID + tid * 8;
  short8 o;
#pragma unroll
  for (int q = 0; q < 8; ++q) {
    float v = (q < 4) ? a[q] : b[q - 4];
    float t = (v - mu) * rstd * gp[q] + bp[q];
    o[q] = (short)f2h(gelu_exact(t));
  }
  *(short8*)(dst + (size_t)(g - c0) * HID + tid * 8) = o;
}

// fallback diagnostic: encode ws_size (MB) into out[0]
__global__ void probe_kernel(float* out, float v) {
  if (threadIdx.x == 0 && blockIdx.x == 0) out[0] = v;
}

extern "C" void kernel_launch(void* const* d_in, const int* in_sizes, int n_in,
                              void* d_out, int out_size, void* d_ws, size_t ws_size,
                              hipStream_t stream) {
  (void)in_sizes; (void)n_in;
  const float* x   = (const float*)d_in[0];
  const float* Wg1 = (const float*)d_in[1];
  const float* Wg2 = (const float*)d_in[2];
  const float* W1  = (const float*)d_in[3];
  const float* b1  = (const float*)d_in[4];
  const float* g1  = (const float*)d_in[5];
  const float* be1 = (const float*)d_in[6];
  const float* W2  = (const float*)d_in[7];
  const float* b2  = (const float*)d_in[8];
  const float* g2  = (const float*)d_in[9];
  const float* be2 = (const float*)d_in[10];
  const float* W3  = (const float*)d_in[11];
  const float* b3  = (const float*)d_in[12];
  float* out = (float*)d_out;

  uint8_t* w = (uint8_t*)d_ws;
  auto alloc = [&](size_t bytes) {
    uint8_t* p = w;
    w += (bytes + 255) & ~(size_t)255;
    return p;
  };
  unsigned short* xh   = (unsigned short*)alloc((size_t)N_TOK * DIM * 2);
  unsigned short* Wt1  = (unsigned short*)alloc((size_t)NEXP * DIM * HID * 2);
  unsigned short* Wt2  = (unsigned short*)alloc((size_t)NEXP * HID * HID * 2);
  unsigned short* Wt3  = (unsigned short*)alloc((size_t)NEXP * HID * OUTD * 2);
  int*   rows  = (int*)alloc((size_t)PADTOT * 4);
  float* roww  = (float*)alloc((size_t)PADTOT * 4);
  int*   tok_e = (int*)alloc((size_t)2 * N_TOK * 4);
  float* tok_w = (float*)alloc((size_t)2 * N_TOK * 4);
  int*   cnt   = (int*)alloc(256);
  int*   off   = (int*)alloc(256);
  int*   cur   = (int*)alloc(256);
  size_t fixed_used = (size_t)(w - (uint8_t*)d_ws);

  // adaptive chunk rows: act1f (fp32, R*HID) + act2 (fp16, R*HID) = 12288 B/row
  long long availLL = (long long)ws_size - (long long)fixed_used - 4096;
  int R = 0;
  if (availLL > 0) {
    long long r = availLL / (HID * 4 + HID * 2);
    if (r > PADTOT) r = PADTOT;
    R = (int)(r & ~127LL);
  }
  if (R < 128) {   // diagnostic fallback: out[0] = ws_size in MB
    hipMemsetAsync(d_out, 0, (size_t)out_size * sizeof(float), stream);
    probe_kernel<<<1, 64, 0, stream>>>(out, (float)(ws_size >> 20));
    return;
  }
  float*          act1f = (float*)alloc((size_t)R * HID * 4);
  unsigned short* act2  = (unsigned short*)alloc((size_t)R * HID * 2);

  hipMemsetAsync(d_out, 0, (size_t)out_size * sizeof(float), stream);  // atomic target
  hipMemsetAsync(cnt, 0, NEXP * sizeof(int), stream);
  hipMemsetAsync(rows, 0, (size_t)PADTOT * 4, stream);   // dummy rows -> token 0
  hipMemsetAsync(roww, 0, (size_t)PADTOT * 4, stream);   // dummy weight -> 0.0

  gate_kernel<<<256, 256, 0, stream>>>(x, Wg1, Wg2, tok_e, tok_w, cnt);
  offsets_kernel<<<1, 64, 0, stream>>>(cnt, off, cur);
  scatter_kernel<<<N_TOK / 256, 256, 0, stream>>>(tok_e, tok_w, cur, rows, roww);

  convert_x_kernel<<<(N_TOK * DIM / 8) / 256, 256, 0, stream>>>(x, xh);
  wconv_kernel<<<dim3(HID / 32, DIM / 32, NEXP), 256, 0, stream>>>(W1, Wt1, DIM, HID);
  wconv_kernel<<<dim3(HID / 32, HID / 32, NEXP), 256, 0, stream>>>(W2, Wt2, HID, HID);
  wconv_kernel<<<dim3(OUTD / 32, HID / 32, NEXP), 256, 0, stream>>>(W3, Wt3, HID, OUTD);

  for (int c0 = 0; c0 < PADTOT; c0 += R) {
    int Rc = PADTOT - c0; if (Rc > R) Rc = R;
    dim3 g1d(HID / 128, Rc / 128), g2d(HID / 128, Rc / 128), g3d(OUTD / 128, Rc / 128);
    gemm_kernel<0><<<g1d, 256, 0, stream>>>(xh, Wt1, act1f, b1, rows, roww, off,
                                            DIM, HID, DIM, c0);
    ln_gelu_kernel<<<Rc, 256, 0, stream>>>(act1f, act2, g1, be1, off, c0);
    gemm_kernel<1><<<g2d, 256, 0, stream>>>(act2, Wt2, act1f, b2, rows, roww, off,
                                            HID, HID, HID, c0);
    ln_gelu_kernel<<<Rc, 256, 0, stream>>>(act1f, act2, g2, be2, off, c0);
    gemm_kernel<2><<<g3d, 256, 0, stream>>>(act2, Wt3, out, b3, rows, roww, off,
                                            HID, OUTD, HID, c0);
  }
}